// Round 2
// 130.415 us; speedup vs baseline: 1.0161x; 1.0161x over previous
//
#include <hip/hip_runtime.h>
#include <hip/hip_bf16.h>
#include <stdint.h>

// LePEAttention, fully-chained MFMA version — 8-wave occupancy split.
// B=4, C=64, H=W=128, heads=8, hd=8, window=128x2 (256 toks).
// Grid 512 = (b, wj, hf, x); block = (b, wi, ch-half), 512 threads = 8 waves:
// wave w -> head (w&3), q-half (w>>2) (qg 0-7 / 8-15). ONE WAVE per
// (window-head, q-half). S^T via mfma_16x16x32 (A=K,B=Q) -> exp -> pack
// feeds mfma_16x16x16 PV B-operand directly. K/V frags cached per-wave in
// VGPRs; inner loop has zero LDS ops. LePE conv (rpe) into LDS (overlays K).
// LDS 55.3KB shared by 8 waves -> 2 blocks/CU = 16 waves/CU (was 8 with
// 4-wave blocks): doubles latency hiding for the scattered staging gathers
// and the mfma->exp->pack->mfma chains.

typedef __attribute__((ext_vector_type(8))) short bf16x8;
typedef __attribute__((ext_vector_type(4))) short bf16x4;
typedef __attribute__((ext_vector_type(4))) float f32x4;

static __device__ __forceinline__ uint32_t pk2(float x, float y) {
    union { __hip_bfloat162 h2; uint32_t u; } c;
    c.h2 = __float22bfloat162_rn(make_float2(x, y));
    return c.u;
}
static __device__ __forceinline__ float bflo(uint32_t u){ return __uint_as_float(u<<16); }
static __device__ __forceinline__ float bfhi(uint32_t u){ return __uint_as_float(u & 0xffff0000u); }

static __device__ __forceinline__ f32x4 mfma16x16x16bf16(bf16x4 a, bf16x4 b, f32x4 c) {
#if __has_builtin(__builtin_amdgcn_mfma_f32_16x16x16bf16_1k)
    return __builtin_amdgcn_mfma_f32_16x16x16bf16_1k(a, b, c, 0, 0, 0);
#else
    f32x4 d;
    asm volatile("v_mfma_f32_16x16x16_bf16 %0, %1, %2, %3\n\ts_nop 7\n\ts_nop 7"
                 : "=v"(d) : "v"(a), "v"(b), "v"(c));
    return d;
#endif
}

__global__ __launch_bounds__(512, 4)
void lepe_attn(const float* __restrict__ temp,
               const float* __restrict__ conv_w,
               const float* __restrict__ conv_b,
               float* __restrict__ out)
{
    __shared__ __align__(16) char smem[55328];
    char* q_s = smem;            // [256 tok][72B]: 32ch bf16 + pad (scaled Q)
    char* k_s = smem + 18432;    // [256 tok][72B] K; later rpe bf16 [256 tok][72B]
    char* v_t = smem + 36864;    // [32 ch][536B]: tok t at byte 2t+4, zero-padded ends
    float* cw_s = (float*)(smem + 54016);  // 288 conv w + 32 bias

    const int tid  = threadIdx.x;
    const int wave = tid >> 6, lane = tid & 63;
    const int lr = lane & 15, quad = lane >> 4;
    const int head  = wave & 3;          // 4 heads per ch-half
    const int qbase = (wave >> 2) * 8;   // q-half: qg 0-7 or 8-15

    // bid = ((b*8 + wj)*2 + hf)*8 + x : XCD = x; hf-pair + wi-octet share XCD.
    const int bid = blockIdx.x;
    const int x  = bid & 7;
    int t_ = bid >> 3;
    const int hf = t_ & 1;  t_ >>= 1;
    const int wj = t_ & 7;
    const int b  = t_ >> 3;
    const int wi = x * 8 + wj;
    const int c0 = hf * 32;

    const size_t cstr = 16384, sstr = 64 * cstr;
    const float qs = 0.35355339059327373f * 1.4426950408889634f;  // hd^-0.5 * log2e

    // ---- staging: thread (cg = ch 0..31, hh0 = row-group 0..15) ----
    {
        const int cg = tid & 31, hh0 = tid >> 5;
        const float* qp = temp + (size_t)b*3*sstr + (size_t)(c0+cg)*cstr + wi*2;
        #pragma unroll
        for (int i = 0; i < 8; ++i) {
            int h = i*16 + hh0;
            float2 fq = *(const float2*)(qp + (size_t)h*128);
            uint32_t uq = pk2(fq.x*qs, fq.y*qs);
            *(uint16_t*)(q_s + (2*h)*72   + cg*2) = (uint16_t)uq;
            *(uint16_t*)(q_s + (2*h+1)*72 + cg*2) = (uint16_t)(uq>>16);
            float2 fk = *(const float2*)(qp + sstr + (size_t)h*128);
            uint32_t uk = pk2(fk.x, fk.y);
            *(uint16_t*)(k_s + (2*h)*72   + cg*2) = (uint16_t)uk;
            *(uint16_t*)(k_s + (2*h+1)*72 + cg*2) = (uint16_t)(uk>>16);
            float2 fv = *(const float2*)(qp + 2*sstr + (size_t)h*128);
            *(uint32_t*)(v_t + cg*536 + 4*h + 4) = pk2(fv.x, fv.y);
        }
        for (int j = tid; j < 288; j += 512) cw_s[j] = conv_w[c0*9 + j];
        if (tid < 32) {
            *(uint32_t*)(v_t + tid*536)       = 0;   // toks -2,-1
            *(uint32_t*)(v_t + tid*536 + 516) = 0;   // toks 256,257
            cw_s[288 + tid] = conv_b[c0 + tid];
        }
    }
    __syncthreads();

    // ---- preload K A-frags (16x b128) and V A-frags (16x b64) into VGPRs ----
    const f32x4 zf = {0.f, 0.f, 0.f, 0.f};
    uint4 kf[16]; uint2 vf[16];
    #pragma unroll
    for (int T = 0; T < 16; ++T) {
        uint4 kk = *(const uint4*)(k_s + (T*16 + lr)*72 + head*16);
        kf[T] = (lane < 16) ? kk : make_uint4(0,0,0,0);
        uint2 vv = *(const uint2*)(v_t + (head*8 + (lane&7))*536 + 4 + (T*16 + quad*4)*2);
        vf[T] = (lr < 8) ? vv : make_uint2(0,0);
    }
    __syncthreads();   // all K frags read; k_s region now free for rpe

    // ---- rpe = depthwise 3x3 conv of V (window-local), bf16 into k_s ----
    {
        const int ch = tid & 31, seg = tid >> 5;     // 16 toks per thread
        const char* base = v_t + ch*536 + seg*32;    // toks seg*16-2 .. +17
        uint32_t d[10];
        *(uint4*)(d+0) = *(const uint4*)(base);
        *(uint4*)(d+4) = *(const uint4*)(base+16);
        *(uint2*)(d+8) = *(const uint2*)(base+32);
        float w9[9];
        #pragma unroll
        for (int k = 0; k < 9; ++k) w9[k] = cw_s[ch*9 + k];
        const float bia = cw_s[288 + ch];
        #pragma unroll
        for (int tt = 0; tt < 16; ++tt) {
            int tok = seg*16 + tt;
            int w01 = tok & 1;
            int L = (tt >> 1) * 2;         // taps = local bf16 idx L..L+5
            float rp = bia;
            #pragma unroll
            for (int dy = 0; dy < 3; ++dy) {
                #pragma unroll
                for (int wp = 0; wp < 2; ++wp) {
                    int idx = L + 2*dy + wp;
                    uint32_t dw = d[idx >> 1];
                    float tap = (idx & 1) ? bfhi(dw) : bflo(dw);
                    rp = fmaf(w9[dy*3 + wp + 1 - w01], tap, rp);
                }
            }
            union { __hip_bfloat16 h; uint16_t u; } cv;
            cv.h = __float2bfloat16(rp);
            *(uint16_t*)(k_s + tok*72 + ch*2) = cv.u;
        }
    }
    __syncthreads();

    // ---- main: per q-group: S^T mfma -> exp -> pack -> PV mfma (chained) ----
    #pragma unroll 1
    for (int qg0 = 0; qg0 < 8; ++qg0) {
        const int qg = qbase + qg0;
        uint4 qq = *(const uint4*)(q_s + (qg*16 + lr)*72 + head*16);
        union { uint4 u; bf16x8 h8; } qf; qf.u = (lane < 16) ? qq : make_uint4(0,0,0,0);
        f32x4 acc = zf;
        float rsum = 0.f;
        #pragma unroll
        for (int T = 0; T < 16; ++T) {
            union { uint4 u; bf16x8 h8; } kfu; kfu.u = kf[T];
            f32x4 sc = __builtin_amdgcn_mfma_f32_16x16x32_bf16(kfu.h8, qf.h8, zf, 0, 0, 0);
            float e0 = __builtin_amdgcn_exp2f(sc[0]);
            float e1 = __builtin_amdgcn_exp2f(sc[1]);
            float e2 = __builtin_amdgcn_exp2f(sc[2]);
            float e3 = __builtin_amdgcn_exp2f(sc[3]);
            rsum += (e0 + e1) + (e2 + e3);
            union { uint2 u; bf16x4 h4; } pb; pb.u = make_uint2(pk2(e0,e1), pk2(e2,e3));
            union { uint2 u; bf16x4 h4; } vfu; vfu.u = vf[T];
            acc = mfma16x16x16bf16(vfu.h4, pb.h4, acc);
        }
        float rs = rsum;
        rs += __shfl_xor(rs, 16);
        rs += __shfl_xor(rs, 32);
        const float rinv = __builtin_amdgcn_rcpf(rs);
        if (quad < 2) {
            int tok = qg*16 + lr;
            int h = tok >> 1, w01 = tok & 1;
            uint2 rp2 = *(const uint2*)(k_s + tok*72 + (head*8 + quad*4)*2);
            float4 ov;
            ov.x = fmaf(acc[0], rinv, bflo(rp2.x));
            ov.y = fmaf(acc[1], rinv, bfhi(rp2.x));
            ov.z = fmaf(acc[2], rinv, bflo(rp2.y));
            ov.w = fmaf(acc[3], rinv, bfhi(rp2.y));
            size_t addr = (size_t)b*1048576 + (size_t)(h*128 + wi*2 + w01)*64
                        + c0 + head*8 + quad*4;
            *(float4*)(out + addr) = ov;
        }
    }
}

extern "C" void kernel_launch(void* const* d_in, const int* in_sizes, int n_in,
                              void* d_out, int out_size, void* d_ws, size_t ws_size,
                              hipStream_t stream) {
    const float* temp = (const float*)d_in[0];
    const float* cw   = (const float*)d_in[1];
    const float* cb   = (const float*)d_in[2];
    float* o = (float*)d_out;
    (void)in_sizes; (void)n_in; (void)out_size; (void)d_ws; (void)ws_size;
    lepe_attn<<<dim3(512), dim3(512), 0, stream>>>(temp, cw, cb, o);
}

// Round 3
// 130.095 us; speedup vs baseline: 1.0186x; 1.0025x over previous
//
#include <hip/hip_runtime.h>
#include <hip/hip_bf16.h>
#include <stdint.h>

// LePEAttention — 8-wave block, register-slim MFMA version.
// B=4, C=64, H=W=128, heads=8, hd=8, window=128x2 (256 toks).
// Grid 512 = (b, wj, hf, x); block = (b, wi, ch-half), 512 threads = 8 waves:
// wave w -> head (w&3), q-half (w>>2). S^T via mfma_16x16x16 (A=K uint2,
// B=Q uint2; hd=8 <= K-dim 16, ch 8-15 zero via quad<2 mask) -> exp -> pack
// feeds mfma_16x16x16 PV B-operand directly. K frags now 32 VGPRs (was 64
// with 16x16x32): total regs/wave ~100 < 128 -> 4 waves/SIMD -> 2 blocks/CU
// co-resident (16 waves/CU) vs 1 block/CU at the old 160-reg footprint.

typedef __attribute__((ext_vector_type(8))) short bf16x8;
typedef __attribute__((ext_vector_type(4))) short bf16x4;
typedef __attribute__((ext_vector_type(4))) float f32x4;

static __device__ __forceinline__ uint32_t pk2(float x, float y) {
    union { __hip_bfloat162 h2; uint32_t u; } c;
    c.h2 = __float22bfloat162_rn(make_float2(x, y));
    return c.u;
}
static __device__ __forceinline__ float bflo(uint32_t u){ return __uint_as_float(u<<16); }
static __device__ __forceinline__ float bfhi(uint32_t u){ return __uint_as_float(u & 0xffff0000u); }

static __device__ __forceinline__ f32x4 mfma16x16x16bf16(bf16x4 a, bf16x4 b, f32x4 c) {
#if __has_builtin(__builtin_amdgcn_mfma_f32_16x16x16bf16_1k)
    return __builtin_amdgcn_mfma_f32_16x16x16bf16_1k(a, b, c, 0, 0, 0);
#else
    f32x4 d;
    asm volatile("v_mfma_f32_16x16x16_bf16 %0, %1, %2, %3\n\ts_nop 7\n\ts_nop 7"
                 : "=v"(d) : "v"(a), "v"(b), "v"(c));
    return d;
#endif
}

__global__ __launch_bounds__(512, 4)
void lepe_attn(const float* __restrict__ temp,
               const float* __restrict__ conv_w,
               const float* __restrict__ conv_b,
               float* __restrict__ out)
{
    __shared__ __align__(16) char smem[55328];
    char* q_s = smem;            // [256 tok][72B]: 32ch bf16 + pad (scaled Q)
    char* k_s = smem + 18432;    // [256 tok][72B] K; later rpe bf16 [256 tok][72B]
    char* v_t = smem + 36864;    // [32 ch][536B]: tok t at byte 2t+4, zero-padded ends
    float* cw_s = (float*)(smem + 54016);  // 288 conv w + 32 bias

    const int tid  = threadIdx.x;
    const int wave = tid >> 6, lane = tid & 63;
    const int lr = lane & 15, quad = lane >> 4;
    const int head  = wave & 3;          // 4 heads per ch-half
    const int qbase = (wave >> 2) * 8;   // q-half: qg 0-7 or 8-15

    // bid = ((b*8 + wj)*2 + hf)*8 + x : XCD = x; hf-pair + wi-octet share XCD.
    const int bid = blockIdx.x;
    const int x  = bid & 7;
    int t_ = bid >> 3;
    const int hf = t_ & 1;  t_ >>= 1;
    const int wj = t_ & 7;
    const int b  = t_ >> 3;
    const int wi = x * 8 + wj;
    const int c0 = hf * 32;

    const size_t cstr = 16384, sstr = 64 * cstr;
    const float qs = 0.35355339059327373f * 1.4426950408889634f;  // hd^-0.5 * log2e

    // ---- staging: thread (cg = ch 0..31, hh0 = row-group 0..15) ----
    {
        const int cg = tid & 31, hh0 = tid >> 5;
        const float* qp = temp + (size_t)b*3*sstr + (size_t)(c0+cg)*cstr + wi*2;
        #pragma unroll
        for (int i = 0; i < 8; ++i) {
            int h = i*16 + hh0;
            float2 fq = *(const float2*)(qp + (size_t)h*128);
            uint32_t uq = pk2(fq.x*qs, fq.y*qs);
            *(uint16_t*)(q_s + (2*h)*72   + cg*2) = (uint16_t)uq;
            *(uint16_t*)(q_s + (2*h+1)*72 + cg*2) = (uint16_t)(uq>>16);
            float2 fk = *(const float2*)(qp + sstr + (size_t)h*128);
            uint32_t uk = pk2(fk.x, fk.y);
            *(uint16_t*)(k_s + (2*h)*72   + cg*2) = (uint16_t)uk;
            *(uint16_t*)(k_s + (2*h+1)*72 + cg*2) = (uint16_t)(uk>>16);
            float2 fv = *(const float2*)(qp + 2*sstr + (size_t)h*128);
            *(uint32_t*)(v_t + cg*536 + 4*h + 4) = pk2(fv.x, fv.y);
        }
        for (int j = tid; j < 288; j += 512) cw_s[j] = conv_w[c0*9 + j];
        if (tid < 32) {
            *(uint32_t*)(v_t + tid*536)       = 0;   // toks -2,-1
            *(uint32_t*)(v_t + tid*536 + 516) = 0;   // toks 256,257
            cw_s[288 + tid] = conv_b[c0 + tid];
        }
    }
    __syncthreads();

    // ---- preload K A-frags (16x b64, quad<2 active) and V A-frags (16x b64) ----
    const f32x4 zf = {0.f, 0.f, 0.f, 0.f};
    const uint2 z2 = make_uint2(0, 0);
    uint2 kf[16]; uint2 vf[16];
    #pragma unroll
    for (int T = 0; T < 16; ++T) {
        uint2 kk = *(const uint2*)(k_s + (T*16 + lr)*72 + head*16 + (quad & 1)*8);
        kf[T] = (quad < 2) ? kk : z2;
        uint2 vv = *(const uint2*)(v_t + (head*8 + (lane&7))*536 + 4 + (T*16 + quad*4)*2);
        vf[T] = (lr < 8) ? vv : z2;
    }
    __syncthreads();   // all K frags read; k_s region now free for rpe

    // ---- rpe = depthwise 3x3 conv of V (window-local), bf16 into k_s ----
    {
        const int ch = tid & 31, seg = tid >> 5;     // 16 toks per thread
        const char* base = v_t + ch*536 + seg*32;    // toks seg*16-2 .. +17
        uint32_t d[10];
        *(uint4*)(d+0) = *(const uint4*)(base);
        *(uint4*)(d+4) = *(const uint4*)(base+16);
        *(uint2*)(d+8) = *(const uint2*)(base+32);
        float w9[9];
        #pragma unroll
        for (int k = 0; k < 9; ++k) w9[k] = cw_s[ch*9 + k];
        const float bia = cw_s[288 + ch];
        #pragma unroll
        for (int tt = 0; tt < 16; ++tt) {
            int tok = seg*16 + tt;
            int w01 = tok & 1;
            int L = (tt >> 1) * 2;         // taps = local bf16 idx L..L+5
            float rp = bia;
            #pragma unroll
            for (int dy = 0; dy < 3; ++dy) {
                #pragma unroll
                for (int wp = 0; wp < 2; ++wp) {
                    int idx = L + 2*dy + wp;
                    uint32_t dw = d[idx >> 1];
                    float tap = (idx & 1) ? bfhi(dw) : bflo(dw);
                    rp = fmaf(w9[dy*3 + wp + 1 - w01], tap, rp);
                }
            }
            union { __hip_bfloat16 h; uint16_t u; } cv;
            cv.h = __float2bfloat16(rp);
            *(uint16_t*)(k_s + tok*72 + ch*2) = cv.u;
        }
    }
    __syncthreads();

    // ---- main: per q-group: S^T mfma -> exp -> pack -> PV mfma (chained) ----
    #pragma unroll 1
    for (int qg0 = 0; qg0 < 8; ++qg0) {
        const int qg = qbase + qg0;
        uint2 qq = *(const uint2*)(q_s + (qg*16 + lr)*72 + head*16 + (quad & 1)*8);
        union { uint2 u; bf16x4 h4; } qf; qf.u = (quad < 2) ? qq : z2;
        f32x4 acc = zf;
        float rsum = 0.f;
        #pragma unroll
        for (int T = 0; T < 16; ++T) {
            union { uint2 u; bf16x4 h4; } kfu; kfu.u = kf[T];
            f32x4 sc = mfma16x16x16bf16(kfu.h4, qf.h4, zf);
            float e0 = __builtin_amdgcn_exp2f(sc[0]);
            float e1 = __builtin_amdgcn_exp2f(sc[1]);
            float e2 = __builtin_amdgcn_exp2f(sc[2]);
            float e3 = __builtin_amdgcn_exp2f(sc[3]);
            rsum += (e0 + e1) + (e2 + e3);
            union { uint2 u; bf16x4 h4; } pb; pb.u = make_uint2(pk2(e0,e1), pk2(e2,e3));
            union { uint2 u; bf16x4 h4; } vfu; vfu.u = vf[T];
            acc = mfma16x16x16bf16(vfu.h4, pb.h4, acc);
        }
        float rs = rsum;
        rs += __shfl_xor(rs, 16);
        rs += __shfl_xor(rs, 32);
        const float rinv = __builtin_amdgcn_rcpf(rs);
        if (quad < 2) {
            int tok = qg*16 + lr;
            int h = tok >> 1, w01 = tok & 1;
            uint2 rp2 = *(const uint2*)(k_s + tok*72 + (head*8 + quad*4)*2);
            float4 ov;
            ov.x = fmaf(acc[0], rinv, bflo(rp2.x));
            ov.y = fmaf(acc[1], rinv, bfhi(rp2.x));
            ov.z = fmaf(acc[2], rinv, bflo(rp2.y));
            ov.w = fmaf(acc[3], rinv, bfhi(rp2.y));
            size_t addr = (size_t)b*1048576 + (size_t)(h*128 + wi*2 + w01)*64
                        + c0 + head*8 + quad*4;
            *(float4*)(out + addr) = ov;
        }
    }
}

extern "C" void kernel_launch(void* const* d_in, const int* in_sizes, int n_in,
                              void* d_out, int out_size, void* d_ws, size_t ws_size,
                              hipStream_t stream) {
    const float* temp = (const float*)d_in[0];
    const float* cw   = (const float*)d_in[1];
    const float* cb   = (const float*)d_in[2];
    float* o = (float*)d_out;
    (void)in_sizes; (void)n_in; (void)out_size; (void)d_ws; (void)ws_size;
    lepe_attn<<<dim3(512), dim3(512), 0, stream>>>(temp, cw, cb, o);
}

// Round 5
// 115.423 us; speedup vs baseline: 1.1481x; 1.1271x over previous
//
#include <hip/hip_runtime.h>
#include <hip/hip_bf16.h>
#include <stdint.h>

// LePEAttention — coalesced-staging restructure (alignment-safe LDS reads).
// B=4, C=64, H=W=128, heads=8, hd=8, window=128x2 (256 toks).
// Grid 512: bid = ((b*8 + head)*2 + wjh)*8 + x  (x = XCD pin; wjh siblings
// share 64B lines on the same XCD). Block = (b, head: 8ch, x, wjh: 4 windows),
// 512 threads = 8 waves: wave w -> window (w&3), q-half (w>>2).
// Staging COALESCED: per (ch,h) the block needs 32 contiguous bytes
// (4 windows x 2 w-positions), loaded as float4/lane -> ~4-6x fewer L2
// transactions than the old 8B-per-lane 64KB-strided gather (which left the
// kernel request-bound at ~950 GB/s with all pipes <31% busy).
// All LDS b64 reads on the 20B-stride Q/K/rpe tiles are explicit u32 pairs
// (addr can be ==4 mod 8; a uint2* cast would assert align-8 -> UB).
// Math pipeline unchanged: S^T via mfma_16x16x16 (A=K,B=Q, hd=8, quads 2-3
// zero) -> exp2 -> pack feeds PV mfma_16x16x16 B-operand directly (layout
// identity). K/V frags in VGPRs; rpe (depthwise 3x3) overlays K region.

typedef __attribute__((ext_vector_type(4))) short bf16x4;
typedef __attribute__((ext_vector_type(4))) float f32x4;

static __device__ __forceinline__ uint32_t pk2(float x, float y) {
    union { __hip_bfloat162 h2; uint32_t u; } c;
    c.h2 = __float22bfloat162_rn(make_float2(x, y));
    return c.u;
}
static __device__ __forceinline__ float bflo(uint32_t u){ return __uint_as_float(u<<16); }
static __device__ __forceinline__ float bfhi(uint32_t u){ return __uint_as_float(u & 0xffff0000u); }

// 8-byte LDS read at 4-byte alignment: two dword reads (-> ds_read2_b32).
static __device__ __forceinline__ uint2 ld2(const char* p) {
    uint2 r;
    r.x = *(const uint32_t*)(p);
    r.y = *(const uint32_t*)(p + 4);
    return r;
}

static __device__ __forceinline__ f32x4 mfma16x16x16bf16(bf16x4 a, bf16x4 b, f32x4 c) {
#if __has_builtin(__builtin_amdgcn_mfma_f32_16x16x16bf16_1k)
    return __builtin_amdgcn_mfma_f32_16x16x16bf16_1k(a, b, c, 0, 0, 0);
#else
    f32x4 d;
    asm volatile("v_mfma_f32_16x16x16_bf16 %0, %1, %2, %3\n\ts_nop 7\n\ts_nop 7"
                 : "=v"(d) : "v"(a), "v"(b), "v"(c));
    return d;
#endif
}

// LDS layout (58432 B):
//   q_s: [4 win][256 tok][20B stride, 16B = 8ch bf16]   20480 B
//   k_s: same; later rpe bf16 same layout               20480 B
//   v_t: [4 win][8 ch][536B], tok t at byte 2t+4        17152 B
//   cw_s: 72 conv w + 8 bias                              320 B
#define QK_TOK_STR 20
#define QK_WIN_STR 5120
#define V_CH_STR   536
#define V_WIN_STR  4288

__global__ __launch_bounds__(512, 4)
void lepe_attn(const float* __restrict__ temp,
               const float* __restrict__ conv_w,
               const float* __restrict__ conv_b,
               float* __restrict__ out)
{
    __shared__ __align__(16) char smem[58432];
    char* q_s = smem;
    char* k_s = smem + 20480;
    char* v_t = smem + 40960;
    float* cw_s = (float*)(smem + 58112);

    const int tid  = threadIdx.x;
    const int wave = tid >> 6, lane = tid & 63;
    const int lr = lane & 15, quad = lane >> 4;
    const int win   = wave & 3;          // window within the wjh quartet
    const int qbase = (wave >> 2) * 8;   // q-half: qg 0-7 or 8-15

    const int bid = blockIdx.x;
    const int x  = bid & 7;
    int t_ = bid >> 3;
    const int wjh  = t_ & 1;  t_ >>= 1;
    const int head = t_ & 7;
    const int b    = t_ >> 3;
    const int wi   = x*8 + wjh*4 + win;  // this wave's window index

    const size_t cstr = 16384, sstr = 64 * cstr;
    const float qs = 0.35355339059327373f * 1.4426950408889634f;  // hd^-0.5 * log2e

    // ---- staging: wave = channel (0..7); lane -> (h-group, 32B-half) ----
    {
        const int cg = wave;                 // channel within head
        const int hg = lane >> 1, hf1 = lane & 1;
        const int w0 = hf1 * 2;              // local window of this float4
        const float* bp = temp + (size_t)b*3*sstr + (size_t)(head*8 + cg)*cstr
                        + x*16 + wjh*8 + hf1*4;
        #pragma unroll
        for (int i = 0; i < 4; ++i) {
            int h = i*32 + hg;
            float4 fq = *(const float4*)(bp + (size_t)h*128);
            uint32_t a0 = pk2(fq.x*qs, fq.y*qs);
            uint32_t a1 = pk2(fq.z*qs, fq.w*qs);
            *(uint16_t*)(q_s + w0*QK_WIN_STR     + (2*h)*QK_TOK_STR   + cg*2) = (uint16_t)a0;
            *(uint16_t*)(q_s + w0*QK_WIN_STR     + (2*h+1)*QK_TOK_STR + cg*2) = (uint16_t)(a0>>16);
            *(uint16_t*)(q_s + (w0+1)*QK_WIN_STR + (2*h)*QK_TOK_STR   + cg*2) = (uint16_t)a1;
            *(uint16_t*)(q_s + (w0+1)*QK_WIN_STR + (2*h+1)*QK_TOK_STR + cg*2) = (uint16_t)(a1>>16);
            float4 fk = *(const float4*)(bp + sstr + (size_t)h*128);
            uint32_t b0 = pk2(fk.x, fk.y);
            uint32_t b1 = pk2(fk.z, fk.w);
            *(uint16_t*)(k_s + w0*QK_WIN_STR     + (2*h)*QK_TOK_STR   + cg*2) = (uint16_t)b0;
            *(uint16_t*)(k_s + w0*QK_WIN_STR     + (2*h+1)*QK_TOK_STR + cg*2) = (uint16_t)(b0>>16);
            *(uint16_t*)(k_s + (w0+1)*QK_WIN_STR + (2*h)*QK_TOK_STR   + cg*2) = (uint16_t)b1;
            *(uint16_t*)(k_s + (w0+1)*QK_WIN_STR + (2*h+1)*QK_TOK_STR + cg*2) = (uint16_t)(b1>>16);
            float4 fv = *(const float4*)(bp + 2*sstr + (size_t)h*128);
            *(uint32_t*)(v_t + w0*V_WIN_STR     + cg*V_CH_STR + 4*h + 4) = pk2(fv.x, fv.y);
            *(uint32_t*)(v_t + (w0+1)*V_WIN_STR + cg*V_CH_STR + 4*h + 4) = pk2(fv.z, fv.w);
        }
        if (tid < 72) cw_s[tid] = conv_w[head*72 + tid];
        if (tid < 8)  cw_s[72 + tid] = conv_b[head*8 + tid];
        if (tid < 32) {
            int vw = tid >> 3, vc = tid & 7;
            *(uint32_t*)(v_t + vw*V_WIN_STR + vc*V_CH_STR)       = 0;   // toks -2,-1
            *(uint32_t*)(v_t + vw*V_WIN_STR + vc*V_CH_STR + 516) = 0;   // toks 256,257
        }
    }
    __syncthreads();

    // ---- preload K A-frags and V A-frags into VGPRs ----
    const f32x4 zf = {0.f, 0.f, 0.f, 0.f};
    const uint2 z2 = make_uint2(0, 0);
    uint2 kf[16]; uint2 vf[16];
    #pragma unroll
    for (int T = 0; T < 16; ++T) {
        uint2 kk = ld2(k_s + win*QK_WIN_STR + (T*16 + lr)*QK_TOK_STR + (quad & 1)*8);
        kf[T] = (quad < 2) ? kk : z2;
        uint2 vv = ld2(v_t + win*V_WIN_STR + (lane & 7)*V_CH_STR + 4 + (T*16 + quad*4)*2);
        vf[T] = (lr < 8) ? vv : z2;
    }
    __syncthreads();   // all K frags read; k_s region now free for rpe

    // ---- rpe = depthwise 3x3 conv of V (window-local), bf16 into k_s ----
    {
        const int w2  = tid >> 7;            // window 0..3
        const int chl = (tid >> 4) & 7;      // channel 0..7
        const int seg = tid & 15;            // 16 toks per thread
        const char* base = v_t + w2*V_WIN_STR + chl*V_CH_STR + seg*32;  // toks seg*16-2 .. +17
        uint32_t d[10];                      // base is 8-aligned (536,32,4288 all %8==0)
        *(uint2*)(d+0) = *(const uint2*)(base);
        *(uint2*)(d+2) = *(const uint2*)(base+8);
        *(uint2*)(d+4) = *(const uint2*)(base+16);
        *(uint2*)(d+6) = *(const uint2*)(base+24);
        *(uint2*)(d+8) = *(const uint2*)(base+32);
        float w9[9];
        #pragma unroll
        for (int k = 0; k < 9; ++k) w9[k] = cw_s[chl*9 + k];
        const float bia = cw_s[72 + chl];
        #pragma unroll
        for (int tt = 0; tt < 16; ++tt) {
            int tok = seg*16 + tt;
            int w01 = tok & 1;
            int L = (tt >> 1) * 2;           // taps = local bf16 idx L..L+5
            float rp = bia;
            #pragma unroll
            for (int dy = 0; dy < 3; ++dy) {
                #pragma unroll
                for (int wp = 0; wp < 2; ++wp) {
                    int idx = L + 2*dy + wp;
                    uint32_t dw = d[idx >> 1];
                    float tap = (idx & 1) ? bfhi(dw) : bflo(dw);
                    rp = fmaf(w9[dy*3 + wp + 1 - w01], tap, rp);
                }
            }
            union { __hip_bfloat16 h; uint16_t u; } cv;
            cv.h = __float2bfloat16(rp);
            *(uint16_t*)(k_s + w2*QK_WIN_STR + tok*QK_TOK_STR + chl*2) = cv.u;
        }
    }
    __syncthreads();

    // ---- main: per q-group: S^T mfma -> exp -> pack -> PV mfma (chained) ----
    #pragma unroll 1
    for (int qg0 = 0; qg0 < 8; ++qg0) {
        const int qg = qbase + qg0;
        uint2 qq = ld2(q_s + win*QK_WIN_STR + (qg*16 + lr)*QK_TOK_STR + (quad & 1)*8);
        union { uint2 u; bf16x4 h4; } qf; qf.u = (quad < 2) ? qq : z2;
        f32x4 acc = zf;
        float rsum = 0.f;
        #pragma unroll
        for (int T = 0; T < 16; ++T) {
            union { uint2 u; bf16x4 h4; } kfu; kfu.u = kf[T];
            f32x4 sc = mfma16x16x16bf16(kfu.h4, qf.h4, zf);
            float e0 = __builtin_amdgcn_exp2f(sc[0]);
            float e1 = __builtin_amdgcn_exp2f(sc[1]);
            float e2 = __builtin_amdgcn_exp2f(sc[2]);
            float e3 = __builtin_amdgcn_exp2f(sc[3]);
            rsum += (e0 + e1) + (e2 + e3);
            union { uint2 u; bf16x4 h4; } pb; pb.u = make_uint2(pk2(e0,e1), pk2(e2,e3));
            union { uint2 u; bf16x4 h4; } vfu; vfu.u = vf[T];
            acc = mfma16x16x16bf16(vfu.h4, pb.h4, acc);
        }
        float rs = rsum;
        rs += __shfl_xor(rs, 16);
        rs += __shfl_xor(rs, 32);
        const float rinv = __builtin_amdgcn_rcpf(rs);
        if (quad < 2) {
            int tok = qg*16 + lr;
            int h = tok >> 1, w01 = tok & 1;
            uint2 rp2 = ld2(k_s + win*QK_WIN_STR + tok*QK_TOK_STR + quad*8);
            float4 ov;
            ov.x = fmaf(acc[0], rinv, bflo(rp2.x));
            ov.y = fmaf(acc[1], rinv, bfhi(rp2.x));
            ov.z = fmaf(acc[2], rinv, bflo(rp2.y));
            ov.w = fmaf(acc[3], rinv, bfhi(rp2.y));
            size_t addr = (size_t)b*1048576 + (size_t)(h*128 + wi*2 + w01)*64
                        + head*8 + quad*4;
            *(float4*)(out + addr) = ov;
        }
    }
}

extern "C" void kernel_launch(void* const* d_in, const int* in_sizes, int n_in,
                              void* d_out, int out_size, void* d_ws, size_t ws_size,
                              hipStream_t stream) {
    const float* temp = (const float*)d_in[0];
    const float* cw   = (const float*)d_in[1];
    const float* cb   = (const float*)d_in[2];
    float* o = (float*)d_out;
    (void)in_sizes; (void)n_in; (void)out_size; (void)d_ws; (void)ws_size;
    lepe_attn<<<dim3(512), dim3(512), 0, stream>>>(temp, cw, cb, o);
}